// Round 15
// baseline (81.833 us; speedup 1.0000x reference)
//
#include <hip/hip_runtime.h>
#include <hip/hip_bf16.h>

#define N_NODES 50000
#define N_EDGES 600000
#define DIM 128
#define CAP 64            // slots per node; P(deg>=64) ~ 1.6e-28 for Poisson(12)
#define WLDS_STRIDE 136   // 128 + 8 ushort pad: 2-way alias on b128 reads (free)

typedef __attribute__((ext_vector_type(8))) short bf16x8;
typedef __attribute__((ext_vector_type(4))) float floatx4;

// ---------------- prep: Wt[n][k] = bf16(W[k][n]); also zero cnt ----------------
__global__ __launch_bounds__(256) void k_prep(const float* __restrict__ W,
                                              ushort* __restrict__ Wt,
                                              int4* __restrict__ cnt4) {
    int b = blockIdx.x;
    if (b < 16) {
        int idx = (b * 256 + threadIdx.x) * 4;
        float4 v = *(const float4*)(W + idx);
        int k = idx >> 7, n = idx & 127;
        Wt[(size_t)(n + 0) * DIM + k] = __bfloat16_as_ushort(__float2bfloat16(v.x));
        Wt[(size_t)(n + 1) * DIM + k] = __bfloat16_as_ushort(__float2bfloat16(v.y));
        Wt[(size_t)(n + 2) * DIM + k] = __bfloat16_as_ushort(__float2bfloat16(v.z));
        Wt[(size_t)(n + 3) * DIM + k] = __bfloat16_as_ushort(__float2bfloat16(v.w));
    } else {
        int i = (b - 16) * 256 + threadIdx.x;
        if (i < N_NODES / 4) cnt4[i] = make_int4(0, 0, 0, 0);
    }
}

// ---------------- direct bucket fill: PACKED 4B slots ----------------
// slot = src (low 16 bits; 50000 < 65536) | bf16(weight) (high 16 bits).
// Halves the scattered-store payload -> halves dirty-line drain traffic.
__global__ __launch_bounds__(256) void k_fill_direct(
        const int* __restrict__ esrc,
        const int* __restrict__ edst,
        const float* __restrict__ ew,
        int* __restrict__ cnt,
        unsigned* __restrict__ slots) {
    int e = blockIdx.x * blockDim.x + threadIdx.x;
    if (e >= N_EDGES) return;
    int d = edst[e];
    int pos = atomicAdd(&cnt[d], 1);
    if (pos < CAP) {
        unsigned u = (unsigned)esrc[e] |
                     ((unsigned)__bfloat16_as_ushort(__float2bfloat16(ew[e])) << 16);
        slots[(size_t)d * CAP + pos] = u;
    }
}

// ---------------- MFMA GEMM: Y = bf16(X @ W), 128 rows/block, 512 thr -------
// 8 waves share one 34.8 KB W-stage -> ~24 waves/CU (vs 16 at 256 thr).
// Swapped operands (proven r9/r12): lane (m,q) holds Y[wr+m][ct*16+q*4+r].
__global__ __launch_bounds__(512) void gemm_mfma(
        const float* __restrict__ X,
        const ushort* __restrict__ Wt,
        ushort* __restrict__ Y) {
    __shared__ ushort Wlds[DIM * WLDS_STRIDE];   // 34816 B
    int t = threadIdx.x;

#pragma unroll
    for (int i = 0; i < 4; ++i) {
        int g = t + 512 * i;
        int n = g >> 4, c = g & 15;
        *(uint4*)&Wlds[n * WLDS_STRIDE + c * 8] = ((const uint4*)Wt)[g];
    }
    __syncthreads();

    int w = t >> 6, l = t & 63;
    int wr = blockIdx.x * 128 + w * 16;
    int m = l & 15, q = l >> 4;
    int rowA = wr + m;
    if (rowA >= N_NODES) rowA = N_NODES - 1;      // clamp loads; stores guarded
    const float* xp = X + (size_t)rowA * DIM + q * 8;

    floatx4 acc[8];
#pragma unroll
    for (int ct = 0; ct < 8; ++ct)
        acc[ct] = (floatx4){0.f, 0.f, 0.f, 0.f};

    const ushort* wl = &Wlds[m * WLDS_STRIDE + q * 8];
#pragma unroll
    for (int kk = 0; kk < 4; ++kk) {
        float4 x0 = *(const float4*)(xp + kk * 32);
        float4 x1 = *(const float4*)(xp + kk * 32 + 4);
        bf16x8 xf;
        xf[0] = (short)__bfloat16_as_ushort(__float2bfloat16(x0.x));
        xf[1] = (short)__bfloat16_as_ushort(__float2bfloat16(x0.y));
        xf[2] = (short)__bfloat16_as_ushort(__float2bfloat16(x0.z));
        xf[3] = (short)__bfloat16_as_ushort(__float2bfloat16(x0.w));
        xf[4] = (short)__bfloat16_as_ushort(__float2bfloat16(x1.x));
        xf[5] = (short)__bfloat16_as_ushort(__float2bfloat16(x1.y));
        xf[6] = (short)__bfloat16_as_ushort(__float2bfloat16(x1.z));
        xf[7] = (short)__bfloat16_as_ushort(__float2bfloat16(x1.w));
#pragma unroll
        for (int ct = 0; ct < 8; ++ct) {
            bf16x8 wf = *(const bf16x8*)(wl + (size_t)(ct * 16) * WLDS_STRIDE + kk * 32);
            acc[ct] = __builtin_amdgcn_mfma_f32_16x16x32_bf16(wf, xf, acc[ct], 0, 0, 0);
        }
    }

    int row = wr + m;
    if (row < N_NODES) {
        ushort* yp = Y + (size_t)row * DIM + q * 4;
#pragma unroll
        for (int ct = 0; ct < 8; ++ct) {
            ushort4 o;
            o.x = __bfloat16_as_ushort(__float2bfloat16(acc[ct][0]));
            o.y = __bfloat16_as_ushort(__float2bfloat16(acc[ct][1]));
            o.z = __bfloat16_as_ushort(__float2bfloat16(acc[ct][2]));
            o.w = __bfloat16_as_ushort(__float2bfloat16(acc[ct][3]));
            *(ushort4*)(yp + ct * 16) = o;
        }
    }
}

// ---------------- gather: 16 lanes/node, predicated 16-edge prefetch ----------
// Packed slots: 4 uint4 loads per 16-edge chunk, then ALL 16 Y uint4 loads
// issued together (one slot-latency + one Y-latency per chunk; deg<=16 for
// ~90% of nodes).
__device__ __forceinline__ float bf_lo(unsigned u) {
    return __uint_as_float(u << 16);
}
__device__ __forceinline__ float bf_hi(unsigned u) {
    return __uint_as_float(u & 0xFFFF0000u);
}

#define ACC8(A, W, Y4)                                        \
    A[0] += (W) * bf_lo((Y4).x); A[1] += (W) * bf_hi((Y4).x); \
    A[2] += (W) * bf_lo((Y4).y); A[3] += (W) * bf_hi((Y4).y); \
    A[4] += (W) * bf_lo((Y4).z); A[5] += (W) * bf_hi((Y4).z); \
    A[6] += (W) * bf_lo((Y4).w); A[7] += (W) * bf_hi((Y4).w);

__global__ __launch_bounds__(256) void k_gather_pf(
        const ushort* __restrict__ Y,
        const int* __restrict__ cnt,
        const unsigned* __restrict__ slots,
        const float* __restrict__ bias,
        float* __restrict__ out) {
    int node = blockIdx.x * 16 + (threadIdx.x >> 4);
    if (node >= N_NODES) return;
    int c = (threadIdx.x & 15) * 8;           // 8 dims per lane
    int deg = cnt[node];
    if (deg > CAP) deg = CAP;
    const uint4* sp4 = (const uint4*)(slots + (size_t)node * CAP);

    float a0[8], a1[8];
#pragma unroll
    for (int k = 0; k < 8; ++k) { a0[k] = 0.f; a1[k] = 0.f; }

    for (int base = 0; base < deg; base += 16) {
        int   idx[16];
        float wgt[16];
#pragma unroll
        for (int i = 0; i < 4; ++i) {
            uint4 sv = sp4[(base >> 2) + i];
            int j = base + 4 * i;
            idx[4 * i + 0] = (j + 0 < deg) ? (int)(sv.x & 0xFFFFu) : 0;
            wgt[4 * i + 0] = (j + 0 < deg) ? bf_hi(sv.x) : 0.f;
            idx[4 * i + 1] = (j + 1 < deg) ? (int)(sv.y & 0xFFFFu) : 0;
            wgt[4 * i + 1] = (j + 1 < deg) ? bf_hi(sv.y) : 0.f;
            idx[4 * i + 2] = (j + 2 < deg) ? (int)(sv.z & 0xFFFFu) : 0;
            wgt[4 * i + 2] = (j + 2 < deg) ? bf_hi(sv.z) : 0.f;
            idx[4 * i + 3] = (j + 3 < deg) ? (int)(sv.w & 0xFFFFu) : 0;
            wgt[4 * i + 3] = (j + 3 < deg) ? bf_hi(sv.w) : 0.f;
        }

        uint4 y[16];
#pragma unroll
        for (int i = 0; i < 16; ++i)
            y[i] = *(const uint4*)(Y + (size_t)idx[i] * DIM + c);

#pragma unroll
        for (int i = 0; i < 16; i += 2) {
            ACC8(a0, wgt[i], y[i]);
            ACC8(a1, wgt[i + 1], y[i + 1]);
        }
    }

    float4 bA = *(const float4*)(bias + c);
    float4 bB = *(const float4*)(bias + c + 4);
    float* op = out + (size_t)node * DIM + c;
    *(float4*)(op + 0) = make_float4(a0[0] + a1[0] + bA.x, a0[1] + a1[1] + bA.y,
                                     a0[2] + a1[2] + bA.z, a0[3] + a1[3] + bA.w);
    *(float4*)(op + 4) = make_float4(a0[4] + a1[4] + bB.x, a0[5] + a1[5] + bB.y,
                                     a0[6] + a1[6] + bB.z, a0[7] + a1[7] + bB.w);
}

// ---------------- fallback path kernels (ws too small) ----------------
__global__ void zero_ws(float4* __restrict__ p, int n4) {
    int i = blockIdx.x * blockDim.x + threadIdx.x;
    if (i < n4) p[i] = make_float4(0.f, 0.f, 0.f, 0.f);
}

__global__ __launch_bounds__(256) void scatter_edges(
        const float* __restrict__ x,
        const float* __restrict__ ew,
        const int* __restrict__ esrc,
        const int* __restrict__ edst,
        float* __restrict__ agg) {
    long long t = (long long)blockIdx.x * blockDim.x + threadIdx.x;
    int e = (int)(t >> 5);
    if (e >= N_EDGES) return;
    int d4 = ((int)t & 31) * 4;
    int s = esrc[e];
    int d = edst[e];
    float w = ew[e];
    float4 xv = *(const float4*)(x + (size_t)s * DIM + d4);
    float* ap = agg + (size_t)d * DIM + d4;
    atomicAdd(ap + 0, w * xv.x);
    atomicAdd(ap + 1, w * xv.y);
    atomicAdd(ap + 2, w * xv.z);
    atomicAdd(ap + 3, w * xv.w);
}

__global__ __launch_bounds__(256) void gemm_f32_bias(
        const float* __restrict__ A,
        const float* __restrict__ W,
        const float* __restrict__ bias,
        float* __restrict__ out) {
    __shared__ float Ws[DIM][DIM];
    int tid = threadIdx.x;
    const float4* W4 = (const float4*)W;
    float4* Ws4 = (float4*)&Ws[0][0];
#pragma unroll
    for (int i = 0; i < 16; ++i) Ws4[tid + 256 * i] = W4[tid + 256 * i];
    __syncthreads();

    int row0 = blockIdx.x * 64 + (tid >> 5) * 8;
    int cg = (tid & 31) * 4;
    float4 b = *(const float4*)(bias + cg);
    float acc[8][4];
#pragma unroll
    for (int i = 0; i < 8; ++i) {
        acc[i][0] = b.x; acc[i][1] = b.y; acc[i][2] = b.z; acc[i][3] = b.w;
    }
    int rload[8];
#pragma unroll
    for (int i = 0; i < 8; ++i) {
        int r = row0 + i;
        rload[i] = (r < N_NODES) ? r : (N_NODES - 1);
    }
    for (int kt = 0; kt < 32; ++kt) {
        float4 xr[8];
#pragma unroll
        for (int i = 0; i < 8; ++i)
            xr[i] = *(const float4*)(A + (size_t)rload[i] * DIM + kt * 4);
        float4 wr[4];
#pragma unroll
        for (int j = 0; j < 4; ++j)
            wr[j] = *(const float4*)&Ws[kt * 4 + j][cg];
#pragma unroll
        for (int i = 0; i < 8; ++i) {
            acc[i][0] += xr[i].x * wr[0].x + xr[i].y * wr[1].x + xr[i].z * wr[2].x + xr[i].w * wr[3].x;
            acc[i][1] += xr[i].x * wr[0].y + xr[i].y * wr[1].y + xr[i].z * wr[2].y + xr[i].w * wr[3].y;
            acc[i][2] += xr[i].x * wr[0].z + xr[i].y * wr[1].z + xr[i].z * wr[2].z + xr[i].w * wr[3].z;
            acc[i][3] += xr[i].x * wr[0].w + xr[i].y * wr[1].w + xr[i].z * wr[2].w + xr[i].w * wr[3].w;
        }
    }
#pragma unroll
    for (int i = 0; i < 8; ++i) {
        int row = row0 + i;
        if (row >= N_NODES) break;
        *(float4*)(out + (size_t)row * DIM + cg) =
            make_float4(acc[i][0], acc[i][1], acc[i][2], acc[i][3]);
    }
}

extern "C" void kernel_launch(void* const* d_in, const int* in_sizes, int n_in,
                              void* d_out, int out_size, void* d_ws, size_t ws_size,
                              hipStream_t stream) {
    const float* batch_x     = (const float*)d_in[0];
    const float* edge_weight = (const float*)d_in[1];
    const float* weight      = (const float*)d_in[2];
    const float* bias        = (const float*)d_in[3];
    const int*   edge_src    = (const int*)d_in[4];
    const int*   edge_dst    = (const int*)d_in[5];
    float* out = (float*)d_out;

    auto align256 = [](size_t x) { return (x + 255) & ~(size_t)255; };
    char* ws = (char*)d_ws;

    size_t oY    = 0;                                                          // 12.8 MB
    size_t oCnt  = align256(oY + (size_t)N_NODES * DIM * sizeof(ushort));      // 200 KB
    size_t oSlot = align256(oCnt + (size_t)N_NODES * sizeof(int));             // 12.8 MB
    size_t oWt   = align256(oSlot + (size_t)N_NODES * CAP * sizeof(unsigned)); // 32 KB
    size_t needed = oWt + (size_t)DIM * DIM * sizeof(ushort);

    if (ws_size >= needed) {
        ushort*   Y    = (ushort*)(ws + oY);
        int*      cnt  = (int*)(ws + oCnt);
        unsigned* slot = (unsigned*)(ws + oSlot);
        ushort*   Wt   = (ushort*)(ws + oWt);

        // 1) prep W (transpose+bf16) and zero counters
        k_prep<<<16 + (N_NODES / 4 + 255) / 256, 256, 0, stream>>>(
            weight, Wt, (int4*)cnt);

        // 2) direct bucket fill (packed 4B slots)
        k_fill_direct<<<(N_EDGES + 255) / 256, 256, 0, stream>>>(
            edge_src, edge_dst, edge_weight, cnt, slot);

        // 3) Y = bf16(X @ W) via MFMA (128 rows/block, 512 threads)
        gemm_mfma<<<(N_NODES + 127) / 128, 512, 0, stream>>>(batch_x, Wt, Y);

        // 4) gather + bias (predicated 16-edge prefetch, packed slots)
        k_gather_pf<<<(N_NODES + 15) / 16, 256, 0, stream>>>(
            Y, cnt, slot, bias, out);
    } else {
        // fallback: atomic path (needs 25.6 MB)
        float* agg = (float*)d_ws;
        int n4 = N_NODES * DIM / 4;
        zero_ws<<<(n4 + 255) / 256, 256, 0, stream>>>((float4*)agg, n4);
        long long threads = (long long)N_EDGES * 32;
        scatter_edges<<<(int)((threads + 255) / 256), 256, 0, stream>>>(
            batch_x, edge_weight, edge_src, edge_dst, agg);
        gemm_f32_bias<<<(N_NODES + 63) / 64, 256, 0, stream>>>(
            agg, weight, bias, out);
    }
}

// Round 16
// 78.397 us; speedup vs baseline: 1.0438x; 1.0438x over previous
//
#include <hip/hip_runtime.h>
#include <hip/hip_bf16.h>

#define N_NODES 50000
#define N_EDGES 600000
#define DIM 128
#define CAP 64            // total slots per node (A+B); P(deg>=64) ~ 1.6e-28
#define CAP_A 16          // primary: 16 x 4B = one 64B line per node (L2-resident)
#define CAP_B 48          // overflow: touched by ~2% of edges
#define WLDS_STRIDE 136   // 128 + 8 ushort pad: 2-way alias on b128 reads (free)

typedef __attribute__((ext_vector_type(8))) short bf16x8;
typedef __attribute__((ext_vector_type(4))) float floatx4;

// ---------------- prep: Wt[n][k] = bf16(W[k][n]); also zero cnt ----------------
__global__ __launch_bounds__(256) void k_prep(const float* __restrict__ W,
                                              ushort* __restrict__ Wt,
                                              int4* __restrict__ cnt4) {
    int b = blockIdx.x;
    if (b < 16) {
        int idx = (b * 256 + threadIdx.x) * 4;
        float4 v = *(const float4*)(W + idx);
        int k = idx >> 7, n = idx & 127;
        Wt[(size_t)(n + 0) * DIM + k] = __bfloat16_as_ushort(__float2bfloat16(v.x));
        Wt[(size_t)(n + 1) * DIM + k] = __bfloat16_as_ushort(__float2bfloat16(v.y));
        Wt[(size_t)(n + 2) * DIM + k] = __bfloat16_as_ushort(__float2bfloat16(v.z));
        Wt[(size_t)(n + 3) * DIM + k] = __bfloat16_as_ushort(__float2bfloat16(v.w));
    } else {
        int i = (b - 16) * 256 + threadIdx.x;
        if (i < N_NODES / 4) cnt4[i] = make_int4(0, 0, 0, 0);
    }
}

// ---------------- direct bucket fill: two-level packed slots ----------------
// slot = src (low 16; 50000 < 65536) | bf16(weight) (high 16).
// pos < 16 -> A (one 64B line per node, L2-resident during the kernel);
// else     -> B (rare overflow, ~12k edges).
__global__ __launch_bounds__(256) void k_fill_ab(
        const int* __restrict__ esrc,
        const int* __restrict__ edst,
        const float* __restrict__ ew,
        int* __restrict__ cnt,
        unsigned* __restrict__ slotA,
        unsigned* __restrict__ slotB) {
    int e = blockIdx.x * blockDim.x + threadIdx.x;
    if (e >= N_EDGES) return;
    int d = edst[e];
    int pos = atomicAdd(&cnt[d], 1);
    unsigned u = (unsigned)esrc[e] |
                 ((unsigned)__bfloat16_as_ushort(__float2bfloat16(ew[e])) << 16);
    if (pos < CAP_A)
        slotA[(size_t)d * CAP_A + pos] = u;
    else if (pos < CAP)
        slotB[(size_t)d * CAP_B + (pos - CAP_A)] = u;
}

// ---------------- MFMA GEMM (verbatim r15): Y = bf16(X @ W), 128 rows/block --
__global__ __launch_bounds__(512) void gemm_mfma(
        const float* __restrict__ X,
        const ushort* __restrict__ Wt,
        ushort* __restrict__ Y) {
    __shared__ ushort Wlds[DIM * WLDS_STRIDE];   // 34816 B
    int t = threadIdx.x;

#pragma unroll
    for (int i = 0; i < 4; ++i) {
        int g = t + 512 * i;
        int n = g >> 4, c = g & 15;
        *(uint4*)&Wlds[n * WLDS_STRIDE + c * 8] = ((const uint4*)Wt)[g];
    }
    __syncthreads();

    int w = t >> 6, l = t & 63;
    int wr = blockIdx.x * 128 + w * 16;
    int m = l & 15, q = l >> 4;
    int rowA = wr + m;
    if (rowA >= N_NODES) rowA = N_NODES - 1;      // clamp loads; stores guarded
    const float* xp = X + (size_t)rowA * DIM + q * 8;

    floatx4 acc[8];
#pragma unroll
    for (int ct = 0; ct < 8; ++ct)
        acc[ct] = (floatx4){0.f, 0.f, 0.f, 0.f};

    const ushort* wl = &Wlds[m * WLDS_STRIDE + q * 8];
#pragma unroll
    for (int kk = 0; kk < 4; ++kk) {
        float4 x0 = *(const float4*)(xp + kk * 32);
        float4 x1 = *(const float4*)(xp + kk * 32 + 4);
        bf16x8 xf;
        xf[0] = (short)__bfloat16_as_ushort(__float2bfloat16(x0.x));
        xf[1] = (short)__bfloat16_as_ushort(__float2bfloat16(x0.y));
        xf[2] = (short)__bfloat16_as_ushort(__float2bfloat16(x0.z));
        xf[3] = (short)__bfloat16_as_ushort(__float2bfloat16(x0.w));
        xf[4] = (short)__bfloat16_as_ushort(__float2bfloat16(x1.x));
        xf[5] = (short)__bfloat16_as_ushort(__float2bfloat16(x1.y));
        xf[6] = (short)__bfloat16_as_ushort(__float2bfloat16(x1.z));
        xf[7] = (short)__bfloat16_as_ushort(__float2bfloat16(x1.w));
#pragma unroll
        for (int ct = 0; ct < 8; ++ct) {
            bf16x8 wf = *(const bf16x8*)(wl + (size_t)(ct * 16) * WLDS_STRIDE + kk * 32);
            acc[ct] = __builtin_amdgcn_mfma_f32_16x16x32_bf16(wf, xf, acc[ct], 0, 0, 0);
        }
    }

    int row = wr + m;
    if (row < N_NODES) {
        ushort* yp = Y + (size_t)row * DIM + q * 4;
#pragma unroll
        for (int ct = 0; ct < 8; ++ct) {
            ushort4 o;
            o.x = __bfloat16_as_ushort(__float2bfloat16(acc[ct][0]));
            o.y = __bfloat16_as_ushort(__float2bfloat16(acc[ct][1]));
            o.z = __bfloat16_as_ushort(__float2bfloat16(acc[ct][2]));
            o.w = __bfloat16_as_ushort(__float2bfloat16(acc[ct][3]));
            *(ushort4*)(yp + ct * 16) = o;
        }
    }
}

// ---------------- gather: 16 lanes/node, predicated 16-edge chunks ----------
__device__ __forceinline__ float bf_lo(unsigned u) {
    return __uint_as_float(u << 16);
}
__device__ __forceinline__ float bf_hi(unsigned u) {
    return __uint_as_float(u & 0xFFFF0000u);
}

#define ACC8(A, W, Y4)                                        \
    A[0] += (W) * bf_lo((Y4).x); A[1] += (W) * bf_hi((Y4).x); \
    A[2] += (W) * bf_lo((Y4).y); A[3] += (W) * bf_hi((Y4).y); \
    A[4] += (W) * bf_lo((Y4).z); A[5] += (W) * bf_hi((Y4).z); \
    A[6] += (W) * bf_lo((Y4).w); A[7] += (W) * bf_hi((Y4).w);

// process one 16-edge chunk: 4 broadcast uint4 slot loads (predicated), then
// all 16 Y uint4 loads issued together
__device__ __forceinline__ void chunk16(const uint4* __restrict__ s4, int soff,
                                        int base, int deg,
                                        const ushort* __restrict__ Y, int c,
                                        float* a0, float* a1) {
    int   idx[16];
    float wgt[16];
#pragma unroll
    for (int i = 0; i < 4; ++i) {
        uint4 sv = s4[soff + i];
        int j = base + 4 * i;
        idx[4 * i + 0] = (j + 0 < deg) ? (int)(sv.x & 0xFFFFu) : 0;
        wgt[4 * i + 0] = (j + 0 < deg) ? bf_hi(sv.x) : 0.f;
        idx[4 * i + 1] = (j + 1 < deg) ? (int)(sv.y & 0xFFFFu) : 0;
        wgt[4 * i + 1] = (j + 1 < deg) ? bf_hi(sv.y) : 0.f;
        idx[4 * i + 2] = (j + 2 < deg) ? (int)(sv.z & 0xFFFFu) : 0;
        wgt[4 * i + 2] = (j + 2 < deg) ? bf_hi(sv.z) : 0.f;
        idx[4 * i + 3] = (j + 3 < deg) ? (int)(sv.w & 0xFFFFu) : 0;
        wgt[4 * i + 3] = (j + 3 < deg) ? bf_hi(sv.w) : 0.f;
    }
    uint4 y[16];
#pragma unroll
    for (int i = 0; i < 16; ++i)
        y[i] = *(const uint4*)(Y + (size_t)idx[i] * DIM + c);
#pragma unroll
    for (int i = 0; i < 16; i += 2) {
        ACC8(a0, wgt[i], y[i]);
        ACC8(a1, wgt[i + 1], y[i + 1]);
    }
}

__global__ __launch_bounds__(256) void k_gather_ab(
        const ushort* __restrict__ Y,
        const int* __restrict__ cnt,
        const unsigned* __restrict__ slotA,
        const unsigned* __restrict__ slotB,
        const float* __restrict__ bias,
        float* __restrict__ out) {
    int node = blockIdx.x * 16 + (threadIdx.x >> 4);
    if (node >= N_NODES) return;
    int c = (threadIdx.x & 15) * 8;           // 8 dims per lane
    int deg = cnt[node];
    if (deg > CAP) deg = CAP;

    float a0[8], a1[8];
#pragma unroll
    for (int k = 0; k < 8; ++k) { a0[k] = 0.f; a1[k] = 0.f; }

    // chunk 0 from A (covers deg <= 16, ~90% of nodes)
    const uint4* a4 = (const uint4*)(slotA + (size_t)node * CAP_A);
    chunk16(a4, 0, 0, deg, Y, c, a0, a1);

    // overflow chunks from B
    if (deg > CAP_A) {
        const uint4* b4 = (const uint4*)(slotB + (size_t)node * CAP_B);
        for (int base = CAP_A; base < deg; base += 16)
            chunk16(b4, (base - CAP_A) >> 2, base, deg, Y, c, a0, a1);
    }

    float4 bA = *(const float4*)(bias + c);
    float4 bB = *(const float4*)(bias + c + 4);
    float* op = out + (size_t)node * DIM + c;
    *(float4*)(op + 0) = make_float4(a0[0] + a1[0] + bA.x, a0[1] + a1[1] + bA.y,
                                     a0[2] + a1[2] + bA.z, a0[3] + a1[3] + bA.w);
    *(float4*)(op + 4) = make_float4(a0[4] + a1[4] + bB.x, a0[5] + a1[5] + bB.y,
                                     a0[6] + a1[6] + bB.z, a0[7] + a1[7] + bB.w);
}

// ---------------- fallback path kernels (ws too small) ----------------
__global__ void zero_ws(float4* __restrict__ p, int n4) {
    int i = blockIdx.x * blockDim.x + threadIdx.x;
    if (i < n4) p[i] = make_float4(0.f, 0.f, 0.f, 0.f);
}

__global__ __launch_bounds__(256) void scatter_edges(
        const float* __restrict__ x,
        const float* __restrict__ ew,
        const int* __restrict__ esrc,
        const int* __restrict__ edst,
        float* __restrict__ agg) {
    long long t = (long long)blockIdx.x * blockDim.x + threadIdx.x;
    int e = (int)(t >> 5);
    if (e >= N_EDGES) return;
    int d4 = ((int)t & 31) * 4;
    int s = esrc[e];
    int d = edst[e];
    float w = ew[e];
    float4 xv = *(const float4*)(x + (size_t)s * DIM + d4);
    float* ap = agg + (size_t)d * DIM + d4;
    atomicAdd(ap + 0, w * xv.x);
    atomicAdd(ap + 1, w * xv.y);
    atomicAdd(ap + 2, w * xv.z);
    atomicAdd(ap + 3, w * xv.w);
}

__global__ __launch_bounds__(256) void gemm_f32_bias(
        const float* __restrict__ A,
        const float* __restrict__ W,
        const float* __restrict__ bias,
        float* __restrict__ out) {
    __shared__ float Ws[DIM][DIM];
    int tid = threadIdx.x;
    const float4* W4 = (const float4*)W;
    float4* Ws4 = (float4*)&Ws[0][0];
#pragma unroll
    for (int i = 0; i < 16; ++i) Ws4[tid + 256 * i] = W4[tid + 256 * i];
    __syncthreads();

    int row0 = blockIdx.x * 64 + (tid >> 5) * 8;
    int cg = (tid & 31) * 4;
    float4 b = *(const float4*)(bias + cg);
    float acc[8][4];
#pragma unroll
    for (int i = 0; i < 8; ++i) {
        acc[i][0] = b.x; acc[i][1] = b.y; acc[i][2] = b.z; acc[i][3] = b.w;
    }
    int rload[8];
#pragma unroll
    for (int i = 0; i < 8; ++i) {
        int r = row0 + i;
        rload[i] = (r < N_NODES) ? r : (N_NODES - 1);
    }
    for (int kt = 0; kt < 32; ++kt) {
        float4 xr[8];
#pragma unroll
        for (int i = 0; i < 8; ++i)
            xr[i] = *(const float4*)(A + (size_t)rload[i] * DIM + kt * 4);
        float4 wr[4];
#pragma unroll
        for (int j = 0; j < 4; ++j)
            wr[j] = *(const float4*)&Ws[kt * 4 + j][cg];
#pragma unroll
        for (int i = 0; i < 8; ++i) {
            acc[i][0] += xr[i].x * wr[0].x + xr[i].y * wr[1].x + xr[i].z * wr[2].x + xr[i].w * wr[3].x;
            acc[i][1] += xr[i].x * wr[0].y + xr[i].y * wr[1].y + xr[i].z * wr[2].y + xr[i].w * wr[3].y;
            acc[i][2] += xr[i].x * wr[0].z + xr[i].y * wr[1].z + xr[i].z * wr[2].z + xr[i].w * wr[3].z;
            acc[i][3] += xr[i].x * wr[0].w + xr[i].y * wr[1].w + xr[i].z * wr[2].w + xr[i].w * wr[3].w;
        }
    }
#pragma unroll
    for (int i = 0; i < 8; ++i) {
        int row = row0 + i;
        if (row >= N_NODES) break;
        *(float4*)(out + (size_t)row * DIM + cg) =
            make_float4(acc[i][0], acc[i][1], acc[i][2], acc[i][3]);
    }
}

extern "C" void kernel_launch(void* const* d_in, const int* in_sizes, int n_in,
                              void* d_out, int out_size, void* d_ws, size_t ws_size,
                              hipStream_t stream) {
    const float* batch_x     = (const float*)d_in[0];
    const float* edge_weight = (const float*)d_in[1];
    const float* weight      = (const float*)d_in[2];
    const float* bias        = (const float*)d_in[3];
    const int*   edge_src    = (const int*)d_in[4];
    const int*   edge_dst    = (const int*)d_in[5];
    float* out = (float*)d_out;

    auto align256 = [](size_t x) { return (x + 255) & ~(size_t)255; };
    char* ws = (char*)d_ws;

    size_t oY    = 0;                                                           // 12.8 MB
    size_t oCnt  = align256(oY + (size_t)N_NODES * DIM * sizeof(ushort));       // 200 KB
    size_t oA    = align256(oCnt + (size_t)N_NODES * sizeof(int));              // 3.2 MB
    size_t oB    = align256(oA + (size_t)N_NODES * CAP_A * sizeof(unsigned));   // 9.6 MB
    size_t oWt   = align256(oB + (size_t)N_NODES * CAP_B * sizeof(unsigned));   // 32 KB
    size_t needed = oWt + (size_t)DIM * DIM * sizeof(ushort);

    if (ws_size >= needed) {
        ushort*   Y     = (ushort*)(ws + oY);
        int*      cnt   = (int*)(ws + oCnt);
        unsigned* slotA = (unsigned*)(ws + oA);
        unsigned* slotB = (unsigned*)(ws + oB);
        ushort*   Wt    = (ushort*)(ws + oWt);

        // 1) prep W (transpose+bf16) and zero counters
        k_prep<<<16 + (N_NODES / 4 + 255) / 256, 256, 0, stream>>>(
            weight, Wt, (int4*)cnt);

        // 2) two-level bucket fill (A line-per-node, B overflow)
        k_fill_ab<<<(N_EDGES + 255) / 256, 256, 0, stream>>>(
            edge_src, edge_dst, edge_weight, cnt, slotA, slotB);

        // 3) Y = bf16(X @ W) via MFMA (128 rows/block, 512 threads)
        gemm_mfma<<<(N_NODES + 127) / 128, 512, 0, stream>>>(batch_x, Wt, Y);

        // 4) gather + bias (A chunk + rare B chunks)
        k_gather_ab<<<(N_NODES + 15) / 16, 256, 0, stream>>>(
            Y, cnt, slotA, slotB, bias, out);
    } else {
        // fallback: atomic path (needs 25.6 MB)
        float* agg = (float*)d_ws;
        int n4 = N_NODES * DIM / 4;
        zero_ws<<<(n4 + 255) / 256, 256, 0, stream>>>((float4*)agg, n4);
        long long threads = (long long)N_EDGES * 32;
        scatter_edges<<<(int)((threads + 255) / 256), 256, 0, stream>>>(
            batch_x, edge_weight, edge_src, edge_dst, agg);
        gemm_f32_bias<<<(N_NODES + 63) / 64, 256, 0, stream>>>(
            agg, weight, bias, out);
    }
}

// Round 17
// 73.096 us; speedup vs baseline: 1.1195x; 1.0725x over previous
//
#include <hip/hip_runtime.h>
#include <hip/hip_bf16.h>

#define N_NODES 50000
#define N_EDGES 600000
#define DIM 128
#define CAP 64            // total slots per node (A+B); P(deg>=64) ~ 1.6e-28
#define CAP_A 16          // primary: 16 x 4B = one 64B line per node (L2-resident)
#define CAP_B 48          // overflow: touched by ~2% of edges
#define WLDS_STRIDE 136   // 128 + 8 ushort pad: 2-way alias on b128 reads (free)
#define EPB 1536          // edges per gemm block (512 thr x 3)

typedef __attribute__((ext_vector_type(8))) short bf16x8;
typedef __attribute__((ext_vector_type(4))) float floatx4;

// ---------------- prep: Wt[n][k] = bf16(W[k][n]); also zero cnt ----------------
__global__ __launch_bounds__(256) void k_prep(const float* __restrict__ W,
                                              ushort* __restrict__ Wt,
                                              int4* __restrict__ cnt4) {
    int b = blockIdx.x;
    if (b < 16) {
        int idx = (b * 256 + threadIdx.x) * 4;
        float4 v = *(const float4*)(W + idx);
        int k = idx >> 7, n = idx & 127;
        Wt[(size_t)(n + 0) * DIM + k] = __bfloat16_as_ushort(__float2bfloat16(v.x));
        Wt[(size_t)(n + 1) * DIM + k] = __bfloat16_as_ushort(__float2bfloat16(v.y));
        Wt[(size_t)(n + 2) * DIM + k] = __bfloat16_as_ushort(__float2bfloat16(v.z));
        Wt[(size_t)(n + 3) * DIM + k] = __bfloat16_as_ushort(__float2bfloat16(v.w));
    } else {
        int i = (b - 16) * 256 + threadIdx.x;
        if (i < N_NODES / 4) cnt4[i] = make_int4(0, 0, 0, 0);
    }
}

// ---------------- fused MFMA GEMM + edge fill ----------------
// gemm body byte-identical to r16 (proven). Fill woven around it:
// edge loads first, atomics issued before syncthreads (acks return during
// MFMA), slot stores after the MFMA loop.
__global__ __launch_bounds__(512) void k_gemm_fill(
        const float* __restrict__ X,
        const ushort* __restrict__ Wt,
        ushort* __restrict__ Y,
        const int* __restrict__ esrc,
        const int* __restrict__ edst,
        const float* __restrict__ ew,
        int* __restrict__ cnt,
        unsigned* __restrict__ slotA,
        unsigned* __restrict__ slotB) {
    __shared__ ushort Wlds[DIM * WLDS_STRIDE];   // 34816 B
    int t = threadIdx.x;

    // ---- fill phase 1: independent edge loads (coalesced, issue first) ----
    int e0 = blockIdx.x * EPB + t;
    int e1 = e0 + 512, e2 = e0 + 1024;
    bool v0 = e0 < N_EDGES, v1 = e1 < N_EDGES, v2 = e2 < N_EDGES;
    int d0 = v0 ? edst[e0] : 0;
    int d1 = v1 ? edst[e1] : 0;
    int d2 = v2 ? edst[e2] : 0;
    unsigned u0 = v0 ? ((unsigned)esrc[e0] |
        ((unsigned)__bfloat16_as_ushort(__float2bfloat16(ew[e0])) << 16)) : 0u;
    unsigned u1 = v1 ? ((unsigned)esrc[e1] |
        ((unsigned)__bfloat16_as_ushort(__float2bfloat16(ew[e1])) << 16)) : 0u;
    unsigned u2 = v2 ? ((unsigned)esrc[e2] |
        ((unsigned)__bfloat16_as_ushort(__float2bfloat16(ew[e2])) << 16)) : 0u;

    // ---- gemm: stage W into LDS ----
#pragma unroll
    for (int i = 0; i < 4; ++i) {
        int g = t + 512 * i;
        int n = g >> 4, c = g & 15;
        *(uint4*)&Wlds[n * WLDS_STRIDE + c * 8] = ((const uint4*)Wt)[g];
    }

    // ---- fill phase 2: atomics (acks return during MFMA loop) ----
    int pos0 = v0 ? atomicAdd(&cnt[d0], 1) : 0;
    int pos1 = v1 ? atomicAdd(&cnt[d1], 1) : 0;
    int pos2 = v2 ? atomicAdd(&cnt[d2], 1) : 0;

    __syncthreads();

    // ---- gemm body (verbatim r16) ----
    int w = t >> 6, l = t & 63;
    int wr = blockIdx.x * 128 + w * 16;
    int m = l & 15, q = l >> 4;
    int rowA = wr + m;
    if (rowA >= N_NODES) rowA = N_NODES - 1;      // clamp loads; stores guarded
    const float* xp = X + (size_t)rowA * DIM + q * 8;

    floatx4 acc[8];
#pragma unroll
    for (int ct = 0; ct < 8; ++ct)
        acc[ct] = (floatx4){0.f, 0.f, 0.f, 0.f};

    const ushort* wl = &Wlds[m * WLDS_STRIDE + q * 8];
#pragma unroll
    for (int kk = 0; kk < 4; ++kk) {
        float4 x0 = *(const float4*)(xp + kk * 32);
        float4 x1 = *(const float4*)(xp + kk * 32 + 4);
        bf16x8 xf;
        xf[0] = (short)__bfloat16_as_ushort(__float2bfloat16(x0.x));
        xf[1] = (short)__bfloat16_as_ushort(__float2bfloat16(x0.y));
        xf[2] = (short)__bfloat16_as_ushort(__float2bfloat16(x0.z));
        xf[3] = (short)__bfloat16_as_ushort(__float2bfloat16(x0.w));
        xf[4] = (short)__bfloat16_as_ushort(__float2bfloat16(x1.x));
        xf[5] = (short)__bfloat16_as_ushort(__float2bfloat16(x1.y));
        xf[6] = (short)__bfloat16_as_ushort(__float2bfloat16(x1.z));
        xf[7] = (short)__bfloat16_as_ushort(__float2bfloat16(x1.w));
#pragma unroll
        for (int ct = 0; ct < 8; ++ct) {
            bf16x8 wf = *(const bf16x8*)(wl + (size_t)(ct * 16) * WLDS_STRIDE + kk * 32);
            acc[ct] = __builtin_amdgcn_mfma_f32_16x16x32_bf16(wf, xf, acc[ct], 0, 0, 0);
        }
    }

    // ---- fill phase 3: slot stores (pos long since returned) ----
    if (v0) {
        if (pos0 < CAP_A)      slotA[(size_t)d0 * CAP_A + pos0] = u0;
        else if (pos0 < CAP)   slotB[(size_t)d0 * CAP_B + (pos0 - CAP_A)] = u0;
    }
    if (v1) {
        if (pos1 < CAP_A)      slotA[(size_t)d1 * CAP_A + pos1] = u1;
        else if (pos1 < CAP)   slotB[(size_t)d1 * CAP_B + (pos1 - CAP_A)] = u1;
    }
    if (v2) {
        if (pos2 < CAP_A)      slotA[(size_t)d2 * CAP_A + pos2] = u2;
        else if (pos2 < CAP)   slotB[(size_t)d2 * CAP_B + (pos2 - CAP_A)] = u2;
    }

    // ---- gemm: Y stores ----
    int row = wr + m;
    if (row < N_NODES) {
        ushort* yp = Y + (size_t)row * DIM + q * 4;
#pragma unroll
        for (int ct = 0; ct < 8; ++ct) {
            ushort4 o;
            o.x = __bfloat16_as_ushort(__float2bfloat16(acc[ct][0]));
            o.y = __bfloat16_as_ushort(__float2bfloat16(acc[ct][1]));
            o.z = __bfloat16_as_ushort(__float2bfloat16(acc[ct][2]));
            o.w = __bfloat16_as_ushort(__float2bfloat16(acc[ct][3]));
            *(ushort4*)(yp + ct * 16) = o;
        }
    }
}

// ---------------- gather (verbatim r16, proven) ----------------
__device__ __forceinline__ float bf_lo(unsigned u) {
    return __uint_as_float(u << 16);
}
__device__ __forceinline__ float bf_hi(unsigned u) {
    return __uint_as_float(u & 0xFFFF0000u);
}

#define ACC8(A, W, Y4)                                        \
    A[0] += (W) * bf_lo((Y4).x); A[1] += (W) * bf_hi((Y4).x); \
    A[2] += (W) * bf_lo((Y4).y); A[3] += (W) * bf_hi((Y4).y); \
    A[4] += (W) * bf_lo((Y4).z); A[5] += (W) * bf_hi((Y4).z); \
    A[6] += (W) * bf_lo((Y4).w); A[7] += (W) * bf_hi((Y4).w);

__device__ __forceinline__ void chunk16(const uint4* __restrict__ s4, int soff,
                                        int base, int deg,
                                        const ushort* __restrict__ Y, int c,
                                        float* a0, float* a1) {
    int   idx[16];
    float wgt[16];
#pragma unroll
    for (int i = 0; i < 4; ++i) {
        uint4 sv = s4[soff + i];
        int j = base + 4 * i;
        idx[4 * i + 0] = (j + 0 < deg) ? (int)(sv.x & 0xFFFFu) : 0;
        wgt[4 * i + 0] = (j + 0 < deg) ? bf_hi(sv.x) : 0.f;
        idx[4 * i + 1] = (j + 1 < deg) ? (int)(sv.y & 0xFFFFu) : 0;
        wgt[4 * i + 1] = (j + 1 < deg) ? bf_hi(sv.y) : 0.f;
        idx[4 * i + 2] = (j + 2 < deg) ? (int)(sv.z & 0xFFFFu) : 0;
        wgt[4 * i + 2] = (j + 2 < deg) ? bf_hi(sv.z) : 0.f;
        idx[4 * i + 3] = (j + 3 < deg) ? (int)(sv.w & 0xFFFFu) : 0;
        wgt[4 * i + 3] = (j + 3 < deg) ? bf_hi(sv.w) : 0.f;
    }
    uint4 y[16];
#pragma unroll
    for (int i = 0; i < 16; ++i)
        y[i] = *(const uint4*)(Y + (size_t)idx[i] * DIM + c);
#pragma unroll
    for (int i = 0; i < 16; i += 2) {
        ACC8(a0, wgt[i], y[i]);
        ACC8(a1, wgt[i + 1], y[i + 1]);
    }
}

__global__ __launch_bounds__(256) void k_gather_ab(
        const ushort* __restrict__ Y,
        const int* __restrict__ cnt,
        const unsigned* __restrict__ slotA,
        const unsigned* __restrict__ slotB,
        const float* __restrict__ bias,
        float* __restrict__ out) {
    int node = blockIdx.x * 16 + (threadIdx.x >> 4);
    if (node >= N_NODES) return;
    int c = (threadIdx.x & 15) * 8;           // 8 dims per lane
    int deg = cnt[node];
    if (deg > CAP) deg = CAP;

    float a0[8], a1[8];
#pragma unroll
    for (int k = 0; k < 8; ++k) { a0[k] = 0.f; a1[k] = 0.f; }

    const uint4* a4 = (const uint4*)(slotA + (size_t)node * CAP_A);
    chunk16(a4, 0, 0, deg, Y, c, a0, a1);

    if (deg > CAP_A) {
        const uint4* b4 = (const uint4*)(slotB + (size_t)node * CAP_B);
        for (int base = CAP_A; base < deg; base += 16)
            chunk16(b4, (base - CAP_A) >> 2, base, deg, Y, c, a0, a1);
    }

    float4 bA = *(const float4*)(bias + c);
    float4 bB = *(const float4*)(bias + c + 4);
    float* op = out + (size_t)node * DIM + c;
    *(float4*)(op + 0) = make_float4(a0[0] + a1[0] + bA.x, a0[1] + a1[1] + bA.y,
                                     a0[2] + a1[2] + bA.z, a0[3] + a1[3] + bA.w);
    *(float4*)(op + 4) = make_float4(a0[4] + a1[4] + bB.x, a0[5] + a1[5] + bB.y,
                                     a0[6] + a1[6] + bB.z, a0[7] + a1[7] + bB.w);
}

// ---------------- fallback path kernels (ws too small) ----------------
__global__ void zero_ws(float4* __restrict__ p, int n4) {
    int i = blockIdx.x * blockDim.x + threadIdx.x;
    if (i < n4) p[i] = make_float4(0.f, 0.f, 0.f, 0.f);
}

__global__ __launch_bounds__(256) void scatter_edges(
        const float* __restrict__ x,
        const float* __restrict__ ew,
        const int* __restrict__ esrc,
        const int* __restrict__ edst,
        float* __restrict__ agg) {
    long long t = (long long)blockIdx.x * blockDim.x + threadIdx.x;
    int e = (int)(t >> 5);
    if (e >= N_EDGES) return;
    int d4 = ((int)t & 31) * 4;
    int s = esrc[e];
    int d = edst[e];
    float w = ew[e];
    float4 xv = *(const float4*)(x + (size_t)s * DIM + d4);
    float* ap = agg + (size_t)d * DIM + d4;
    atomicAdd(ap + 0, w * xv.x);
    atomicAdd(ap + 1, w * xv.y);
    atomicAdd(ap + 2, w * xv.z);
    atomicAdd(ap + 3, w * xv.w);
}

__global__ __launch_bounds__(256) void gemm_f32_bias(
        const float* __restrict__ A,
        const float* __restrict__ W,
        const float* __restrict__ bias,
        float* __restrict__ out) {
    __shared__ float Ws[DIM][DIM];
    int tid = threadIdx.x;
    const float4* W4 = (const float4*)W;
    float4* Ws4 = (float4*)&Ws[0][0];
#pragma unroll
    for (int i = 0; i < 16; ++i) Ws4[tid + 256 * i] = W4[tid + 256 * i];
    __syncthreads();

    int row0 = blockIdx.x * 64 + (tid >> 5) * 8;
    int cg = (tid & 31) * 4;
    float4 b = *(const float4*)(bias + cg);
    float acc[8][4];
#pragma unroll
    for (int i = 0; i < 8; ++i) {
        acc[i][0] = b.x; acc[i][1] = b.y; acc[i][2] = b.z; acc[i][3] = b.w;
    }
    int rload[8];
#pragma unroll
    for (int i = 0; i < 8; ++i) {
        int r = row0 + i;
        rload[i] = (r < N_NODES) ? r : (N_NODES - 1);
    }
    for (int kt = 0; kt < 32; ++kt) {
        float4 xr[8];
#pragma unroll
        for (int i = 0; i < 8; ++i)
            xr[i] = *(const float4*)(A + (size_t)rload[i] * DIM + kt * 4);
        float4 wr[4];
#pragma unroll
        for (int j = 0; j < 4; ++j)
            wr[j] = *(const float4*)&Ws[kt * 4 + j][cg];
#pragma unroll
        for (int i = 0; i < 8; ++i) {
            acc[i][0] += xr[i].x * wr[0].x + xr[i].y * wr[1].x + xr[i].z * wr[2].x + xr[i].w * wr[3].x;
            acc[i][1] += xr[i].x * wr[0].y + xr[i].y * wr[1].y + xr[i].z * wr[2].y + xr[i].w * wr[3].y;
            acc[i][2] += xr[i].x * wr[0].z + xr[i].y * wr[1].z + xr[i].z * wr[2].z + xr[i].w * wr[3].z;
            acc[i][3] += xr[i].x * wr[0].w + xr[i].y * wr[1].w + xr[i].z * wr[2].w + xr[i].w * wr[3].w;
        }
    }
#pragma unroll
    for (int i = 0; i < 8; ++i) {
        int row = row0 + i;
        if (row >= N_NODES) break;
        *(float4*)(out + (size_t)row * DIM + cg) =
            make_float4(acc[i][0], acc[i][1], acc[i][2], acc[i][3]);
    }
}

extern "C" void kernel_launch(void* const* d_in, const int* in_sizes, int n_in,
                              void* d_out, int out_size, void* d_ws, size_t ws_size,
                              hipStream_t stream) {
    const float* batch_x     = (const float*)d_in[0];
    const float* edge_weight = (const float*)d_in[1];
    const float* weight      = (const float*)d_in[2];
    const float* bias        = (const float*)d_in[3];
    const int*   edge_src    = (const int*)d_in[4];
    const int*   edge_dst    = (const int*)d_in[5];
    float* out = (float*)d_out;

    auto align256 = [](size_t x) { return (x + 255) & ~(size_t)255; };
    char* ws = (char*)d_ws;

    size_t oY    = 0;                                                           // 12.8 MB
    size_t oCnt  = align256(oY + (size_t)N_NODES * DIM * sizeof(ushort));       // 200 KB
    size_t oA    = align256(oCnt + (size_t)N_NODES * sizeof(int));              // 3.2 MB
    size_t oB    = align256(oA + (size_t)N_NODES * CAP_A * sizeof(unsigned));   // 9.6 MB
    size_t oWt   = align256(oB + (size_t)N_NODES * CAP_B * sizeof(unsigned));   // 32 KB
    size_t needed = oWt + (size_t)DIM * DIM * sizeof(ushort);

    int gemm_blocks = (N_NODES + 127) / 128;   // 391; covers 391*1536 >= 600k edges

    if (ws_size >= needed) {
        ushort*   Y     = (ushort*)(ws + oY);
        int*      cnt   = (int*)(ws + oCnt);
        unsigned* slotA = (unsigned*)(ws + oA);
        unsigned* slotB = (unsigned*)(ws + oB);
        ushort*   Wt    = (ushort*)(ws + oWt);

        // 1) prep W (transpose+bf16) and zero counters
        k_prep<<<16 + (N_NODES / 4 + 255) / 256, 256, 0, stream>>>(
            weight, Wt, (int4*)cnt);

        // 2) fused gemm (Y = bf16(X@W)) + edge fill (atomics hidden under MFMA)
        k_gemm_fill<<<gemm_blocks, 512, 0, stream>>>(
            batch_x, Wt, Y, edge_src, edge_dst, edge_weight,
            cnt, slotA, slotB);

        // 3) gather + bias (A chunk + rare B chunks)
        k_gather_ab<<<(N_NODES + 15) / 16, 256, 0, stream>>>(
            Y, cnt, slotA, slotB, bias, out);
    } else {
        // fallback: atomic path (needs 25.6 MB)
        float* agg = (float*)d_ws;
        int n4 = N_NODES * DIM / 4;
        zero_ws<<<(n4 + 255) / 256, 256, 0, stream>>>((float4*)agg, n4);
        long long threads = (long long)N_EDGES * 32;
        scatter_edges<<<(int)((threads + 255) / 256), 256, 0, stream>>>(
            batch_x, edge_weight, edge_src, edge_dst, agg);
        gemm_f32_bias<<<(N_NODES + 63) / 64, 256, 0, stream>>>(
            agg, weight, bias, out);
    }
}

// Round 18
// 68.782 us; speedup vs baseline: 1.1897x; 1.0627x over previous
//
#include <hip/hip_runtime.h>
#include <hip/hip_bf16.h>

#define N_NODES 50000
#define N_EDGES 600000
#define DIM 128
#define CAP 64            // total slots per node (A+B); P(deg>=64) ~ 1.6e-28
#define CAP_A 16          // primary: 16 x 4B = one 64B line per node (L2-resident)
#define CAP_B 48          // overflow: touched by ~2% of edges
#define CNT_STRIDE 16     // one counter per 64B line (kills false sharing)
#define WLDS_STRIDE 136   // 128 + 8 ushort pad: 2-way alias on b128 reads (free)
#define EPB 1536          // edges per gemm block (512 thr x 3)

typedef __attribute__((ext_vector_type(8))) short bf16x8;
typedef __attribute__((ext_vector_type(4))) float floatx4;

// ---------------- prep: Wt[n][k] = bf16(W[k][n]); also zero padded cnt --------
__global__ __launch_bounds__(256) void k_prep(const float* __restrict__ W,
                                              ushort* __restrict__ Wt,
                                              int4* __restrict__ cnt4) {
    int b = blockIdx.x;
    if (b < 16) {
        int idx = (b * 256 + threadIdx.x) * 4;
        float4 v = *(const float4*)(W + idx);
        int k = idx >> 7, n = idx & 127;
        Wt[(size_t)(n + 0) * DIM + k] = __bfloat16_as_ushort(__float2bfloat16(v.x));
        Wt[(size_t)(n + 1) * DIM + k] = __bfloat16_as_ushort(__float2bfloat16(v.y));
        Wt[(size_t)(n + 2) * DIM + k] = __bfloat16_as_ushort(__float2bfloat16(v.z));
        Wt[(size_t)(n + 3) * DIM + k] = __bfloat16_as_ushort(__float2bfloat16(v.w));
    } else {
        int i = (b - 16) * 256 + threadIdx.x;
        if (i < N_NODES * CNT_STRIDE / 4) cnt4[i] = make_int4(0, 0, 0, 0);
    }
}

// ---------------- fused MFMA GEMM + edge fill ----------------
// FIX vs r17: atomics issued AFTER __syncthreads (the barrier's vmcnt(0)
// drain was exposing their latency); now the round trip hides under the
// 32-MFMA loop. Counters padded to one per 64B line.
__global__ __launch_bounds__(512) void k_gemm_fill(
        const float* __restrict__ X,
        const ushort* __restrict__ Wt,
        ushort* __restrict__ Y,
        const int* __restrict__ esrc,
        const int* __restrict__ edst,
        const float* __restrict__ ew,
        int* __restrict__ cnt,
        unsigned* __restrict__ slotA,
        unsigned* __restrict__ slotB) {
    __shared__ ushort Wlds[DIM * WLDS_STRIDE];   // 34816 B
    int t = threadIdx.x;

    // ---- fill phase 1: independent edge loads (coalesced, issue first) ----
    int e0 = blockIdx.x * EPB + t;
    int e1 = e0 + 512, e2 = e0 + 1024;
    bool v0 = e0 < N_EDGES, v1 = e1 < N_EDGES, v2 = e2 < N_EDGES;
    int d0 = v0 ? edst[e0] : 0;
    int d1 = v1 ? edst[e1] : 0;
    int d2 = v2 ? edst[e2] : 0;
    unsigned u0 = v0 ? ((unsigned)esrc[e0] |
        ((unsigned)__bfloat16_as_ushort(__float2bfloat16(ew[e0])) << 16)) : 0u;
    unsigned u1 = v1 ? ((unsigned)esrc[e1] |
        ((unsigned)__bfloat16_as_ushort(__float2bfloat16(ew[e1])) << 16)) : 0u;
    unsigned u2 = v2 ? ((unsigned)esrc[e2] |
        ((unsigned)__bfloat16_as_ushort(__float2bfloat16(ew[e2])) << 16)) : 0u;

    // ---- gemm: stage W into LDS ----
#pragma unroll
    for (int i = 0; i < 4; ++i) {
        int g = t + 512 * i;
        int n = g >> 4, c = g & 15;
        *(uint4*)&Wlds[n * WLDS_STRIDE + c * 8] = ((const uint4*)Wt)[g];
    }

    __syncthreads();

    // ---- fill phase 2: atomics AFTER the barrier; latency hides under MFMA ----
    int pos0 = v0 ? atomicAdd(&cnt[(size_t)d0 * CNT_STRIDE], 1) : 0;
    int pos1 = v1 ? atomicAdd(&cnt[(size_t)d1 * CNT_STRIDE], 1) : 0;
    int pos2 = v2 ? atomicAdd(&cnt[(size_t)d2 * CNT_STRIDE], 1) : 0;

    // ---- gemm body (verbatim r16) ----
    int w = t >> 6, l = t & 63;
    int wr = blockIdx.x * 128 + w * 16;
    int m = l & 15, q = l >> 4;
    int rowA = wr + m;
    if (rowA >= N_NODES) rowA = N_NODES - 1;      // clamp loads; stores guarded
    const float* xp = X + (size_t)rowA * DIM + q * 8;

    floatx4 acc[8];
#pragma unroll
    for (int ct = 0; ct < 8; ++ct)
        acc[ct] = (floatx4){0.f, 0.f, 0.f, 0.f};

    const ushort* wl = &Wlds[m * WLDS_STRIDE + q * 8];
#pragma unroll
    for (int kk = 0; kk < 4; ++kk) {
        float4 x0 = *(const float4*)(xp + kk * 32);
        float4 x1 = *(const float4*)(xp + kk * 32 + 4);
        bf16x8 xf;
        xf[0] = (short)__bfloat16_as_ushort(__float2bfloat16(x0.x));
        xf[1] = (short)__bfloat16_as_ushort(__float2bfloat16(x0.y));
        xf[2] = (short)__bfloat16_as_ushort(__float2bfloat16(x0.z));
        xf[3] = (short)__bfloat16_as_ushort(__float2bfloat16(x0.w));
        xf[4] = (short)__bfloat16_as_ushort(__float2bfloat16(x1.x));
        xf[5] = (short)__bfloat16_as_ushort(__float2bfloat16(x1.y));
        xf[6] = (short)__bfloat16_as_ushort(__float2bfloat16(x1.z));
        xf[7] = (short)__bfloat16_as_ushort(__float2bfloat16(x1.w));
#pragma unroll
        for (int ct = 0; ct < 8; ++ct) {
            bf16x8 wf = *(const bf16x8*)(wl + (size_t)(ct * 16) * WLDS_STRIDE + kk * 32);
            acc[ct] = __builtin_amdgcn_mfma_f32_16x16x32_bf16(wf, xf, acc[ct], 0, 0, 0);
        }
    }

    // ---- fill phase 3: slot stores (pos returned during the MFMA loop) ----
    if (v0) {
        if (pos0 < CAP_A)      slotA[(size_t)d0 * CAP_A + pos0] = u0;
        else if (pos0 < CAP)   slotB[(size_t)d0 * CAP_B + (pos0 - CAP_A)] = u0;
    }
    if (v1) {
        if (pos1 < CAP_A)      slotA[(size_t)d1 * CAP_A + pos1] = u1;
        else if (pos1 < CAP)   slotB[(size_t)d1 * CAP_B + (pos1 - CAP_A)] = u1;
    }
    if (v2) {
        if (pos2 < CAP_A)      slotA[(size_t)d2 * CAP_A + pos2] = u2;
        else if (pos2 < CAP)   slotB[(size_t)d2 * CAP_B + (pos2 - CAP_A)] = u2;
    }

    // ---- gemm: Y stores ----
    int row = wr + m;
    if (row < N_NODES) {
        ushort* yp = Y + (size_t)row * DIM + q * 4;
#pragma unroll
        for (int ct = 0; ct < 8; ++ct) {
            ushort4 o;
            o.x = __bfloat16_as_ushort(__float2bfloat16(acc[ct][0]));
            o.y = __bfloat16_as_ushort(__float2bfloat16(acc[ct][1]));
            o.z = __bfloat16_as_ushort(__float2bfloat16(acc[ct][2]));
            o.w = __bfloat16_as_ushort(__float2bfloat16(acc[ct][3]));
            *(ushort4*)(yp + ct * 16) = o;
        }
    }
}

// ---------------- gather (r16 structure; padded cnt read) ----------------
__device__ __forceinline__ float bf_lo(unsigned u) {
    return __uint_as_float(u << 16);
}
__device__ __forceinline__ float bf_hi(unsigned u) {
    return __uint_as_float(u & 0xFFFF0000u);
}

#define ACC8(A, W, Y4)                                        \
    A[0] += (W) * bf_lo((Y4).x); A[1] += (W) * bf_hi((Y4).x); \
    A[2] += (W) * bf_lo((Y4).y); A[3] += (W) * bf_hi((Y4).y); \
    A[4] += (W) * bf_lo((Y4).z); A[5] += (W) * bf_hi((Y4).z); \
    A[6] += (W) * bf_lo((Y4).w); A[7] += (W) * bf_hi((Y4).w);

__device__ __forceinline__ void chunk16(const uint4* __restrict__ s4, int soff,
                                        int base, int deg,
                                        const ushort* __restrict__ Y, int c,
                                        float* a0, float* a1) {
    int   idx[16];
    float wgt[16];
#pragma unroll
    for (int i = 0; i < 4; ++i) {
        uint4 sv = s4[soff + i];
        int j = base + 4 * i;
        idx[4 * i + 0] = (j + 0 < deg) ? (int)(sv.x & 0xFFFFu) : 0;
        wgt[4 * i + 0] = (j + 0 < deg) ? bf_hi(sv.x) : 0.f;
        idx[4 * i + 1] = (j + 1 < deg) ? (int)(sv.y & 0xFFFFu) : 0;
        wgt[4 * i + 1] = (j + 1 < deg) ? bf_hi(sv.y) : 0.f;
        idx[4 * i + 2] = (j + 2 < deg) ? (int)(sv.z & 0xFFFFu) : 0;
        wgt[4 * i + 2] = (j + 2 < deg) ? bf_hi(sv.z) : 0.f;
        idx[4 * i + 3] = (j + 3 < deg) ? (int)(sv.w & 0xFFFFu) : 0;
        wgt[4 * i + 3] = (j + 3 < deg) ? bf_hi(sv.w) : 0.f;
    }
    uint4 y[16];
#pragma unroll
    for (int i = 0; i < 16; ++i)
        y[i] = *(const uint4*)(Y + (size_t)idx[i] * DIM + c);
#pragma unroll
    for (int i = 0; i < 16; i += 2) {
        ACC8(a0, wgt[i], y[i]);
        ACC8(a1, wgt[i + 1], y[i + 1]);
    }
}

__global__ __launch_bounds__(256) void k_gather_ab(
        const ushort* __restrict__ Y,
        const int* __restrict__ cnt,
        const unsigned* __restrict__ slotA,
        const unsigned* __restrict__ slotB,
        const float* __restrict__ bias,
        float* __restrict__ out) {
    int node = blockIdx.x * 16 + (threadIdx.x >> 4);
    if (node >= N_NODES) return;
    int c = (threadIdx.x & 15) * 8;           // 8 dims per lane
    int deg = cnt[(size_t)node * CNT_STRIDE];
    if (deg > CAP) deg = CAP;

    float a0[8], a1[8];
#pragma unroll
    for (int k = 0; k < 8; ++k) { a0[k] = 0.f; a1[k] = 0.f; }

    const uint4* a4 = (const uint4*)(slotA + (size_t)node * CAP_A);
    chunk16(a4, 0, 0, deg, Y, c, a0, a1);

    if (deg > CAP_A) {
        const uint4* b4 = (const uint4*)(slotB + (size_t)node * CAP_B);
        for (int base = CAP_A; base < deg; base += 16)
            chunk16(b4, (base - CAP_A) >> 2, base, deg, Y, c, a0, a1);
    }

    float4 bA = *(const float4*)(bias + c);
    float4 bB = *(const float4*)(bias + c + 4);
    float* op = out + (size_t)node * DIM + c;
    *(float4*)(op + 0) = make_float4(a0[0] + a1[0] + bA.x, a0[1] + a1[1] + bA.y,
                                     a0[2] + a1[2] + bA.z, a0[3] + a1[3] + bA.w);
    *(float4*)(op + 4) = make_float4(a0[4] + a1[4] + bB.x, a0[5] + a1[5] + bB.y,
                                     a0[6] + a1[6] + bB.z, a0[7] + a1[7] + bB.w);
}

// ---------------- fallback path kernels (ws too small) ----------------
__global__ void zero_ws(float4* __restrict__ p, int n4) {
    int i = blockIdx.x * blockDim.x + threadIdx.x;
    if (i < n4) p[i] = make_float4(0.f, 0.f, 0.f, 0.f);
}

__global__ __launch_bounds__(256) void scatter_edges(
        const float* __restrict__ x,
        const float* __restrict__ ew,
        const int* __restrict__ esrc,
        const int* __restrict__ edst,
        float* __restrict__ agg) {
    long long t = (long long)blockIdx.x * blockDim.x + threadIdx.x;
    int e = (int)(t >> 5);
    if (e >= N_EDGES) return;
    int d4 = ((int)t & 31) * 4;
    int s = esrc[e];
    int d = edst[e];
    float w = ew[e];
    float4 xv = *(const float4*)(x + (size_t)s * DIM + d4);
    float* ap = agg + (size_t)d * DIM + d4;
    atomicAdd(ap + 0, w * xv.x);
    atomicAdd(ap + 1, w * xv.y);
    atomicAdd(ap + 2, w * xv.z);
    atomicAdd(ap + 3, w * xv.w);
}

__global__ __launch_bounds__(256) void gemm_f32_bias(
        const float* __restrict__ A,
        const float* __restrict__ W,
        const float* __restrict__ bias,
        float* __restrict__ out) {
    __shared__ float Ws[DIM][DIM];
    int tid = threadIdx.x;
    const float4* W4 = (const float4*)W;
    float4* Ws4 = (float4*)&Ws[0][0];
#pragma unroll
    for (int i = 0; i < 16; ++i) Ws4[tid + 256 * i] = W4[tid + 256 * i];
    __syncthreads();

    int row0 = blockIdx.x * 64 + (tid >> 5) * 8;
    int cg = (tid & 31) * 4;
    float4 b = *(const float4*)(bias + cg);
    float acc[8][4];
#pragma unroll
    for (int i = 0; i < 8; ++i) {
        acc[i][0] = b.x; acc[i][1] = b.y; acc[i][2] = b.z; acc[i][3] = b.w;
    }
    int rload[8];
#pragma unroll
    for (int i = 0; i < 8; ++i) {
        int r = row0 + i;
        rload[i] = (r < N_NODES) ? r : (N_NODES - 1);
    }
    for (int kt = 0; kt < 32; ++kt) {
        float4 xr[8];
#pragma unroll
        for (int i = 0; i < 8; ++i)
            xr[i] = *(const float4*)(A + (size_t)rload[i] * DIM + kt * 4);
        float4 wr[4];
#pragma unroll
        for (int j = 0; j < 4; ++j)
            wr[j] = *(const float4*)&Ws[kt * 4 + j][cg];
#pragma unroll
        for (int i = 0; i < 8; ++i) {
            acc[i][0] += xr[i].x * wr[0].x + xr[i].y * wr[1].x + xr[i].z * wr[2].x + xr[i].w * wr[3].x;
            acc[i][1] += xr[i].x * wr[0].y + xr[i].y * wr[1].y + xr[i].z * wr[2].y + xr[i].w * wr[3].y;
            acc[i][2] += xr[i].x * wr[0].z + xr[i].y * wr[1].z + xr[i].z * wr[2].z + xr[i].w * wr[3].z;
            acc[i][3] += xr[i].x * wr[0].w + xr[i].y * wr[1].w + xr[i].z * wr[2].w + xr[i].w * wr[3].w;
        }
    }
#pragma unroll
    for (int i = 0; i < 8; ++i) {
        int row = row0 + i;
        if (row >= N_NODES) break;
        *(float4*)(out + (size_t)row * DIM + cg) =
            make_float4(acc[i][0], acc[i][1], acc[i][2], acc[i][3]);
    }
}

extern "C" void kernel_launch(void* const* d_in, const int* in_sizes, int n_in,
                              void* d_out, int out_size, void* d_ws, size_t ws_size,
                              hipStream_t stream) {
    const float* batch_x     = (const float*)d_in[0];
    const float* edge_weight = (const float*)d_in[1];
    const float* weight      = (const float*)d_in[2];
    const float* bias        = (const float*)d_in[3];
    const int*   edge_src    = (const int*)d_in[4];
    const int*   edge_dst    = (const int*)d_in[5];
    float* out = (float*)d_out;

    auto align256 = [](size_t x) { return (x + 255) & ~(size_t)255; };
    char* ws = (char*)d_ws;

    size_t oY    = 0;                                                             // 12.8 MB
    size_t oCnt  = align256(oY + (size_t)N_NODES * DIM * sizeof(ushort));         // 3.2 MB (padded)
    size_t oA    = align256(oCnt + (size_t)N_NODES * CNT_STRIDE * sizeof(int));   // 3.2 MB
    size_t oB    = align256(oA + (size_t)N_NODES * CAP_A * sizeof(unsigned));     // 9.6 MB
    size_t oWt   = align256(oB + (size_t)N_NODES * CAP_B * sizeof(unsigned));     // 32 KB
    size_t needed = oWt + (size_t)DIM * DIM * sizeof(ushort);

    int gemm_blocks = (N_NODES + 127) / 128;   // 391; covers 391*1536 >= 600k edges
    int zero_blocks = (N_NODES * CNT_STRIDE / 4 + 255) / 256;   // 782

    if (ws_size >= needed) {
        ushort*   Y     = (ushort*)(ws + oY);
        int*      cnt   = (int*)(ws + oCnt);
        unsigned* slotA = (unsigned*)(ws + oA);
        unsigned* slotB = (unsigned*)(ws + oB);
        ushort*   Wt    = (ushort*)(ws + oWt);

        // 1) prep W (transpose+bf16) and zero padded counters
        k_prep<<<16 + zero_blocks, 256, 0, stream>>>(weight, Wt, (int4*)cnt);

        // 2) fused gemm (Y = bf16(X@W)) + edge fill (atomics after barrier)
        k_gemm_fill<<<gemm_blocks, 512, 0, stream>>>(
            batch_x, Wt, Y, edge_src, edge_dst, edge_weight,
            cnt, slotA, slotB);

        // 3) gather + bias (A chunk + rare B chunks)
        k_gather_ab<<<(N_NODES + 15) / 16, 256, 0, stream>>>(
            Y, cnt, slotA, slotB, bias, out);
    } else {
        // fallback: atomic path (needs 25.6 MB)
        float* agg = (float*)d_ws;
        int n4 = N_NODES * DIM / 4;
        zero_ws<<<(n4 + 255) / 256, 256, 0, stream>>>((float4*)agg, n4);
        long long threads = (long long)N_EDGES * 32;
        scatter_edges<<<(int)((threads + 255) / 256), 256, 0, stream>>>(
            batch_x, edge_weight, edge_src, edge_dst, agg);
        gemm_f32_bias<<<(N_NODES + 63) / 64, 256, 0, stream>>>(
            agg, weight, bias, out);
    }
}